// Round 7
// baseline (2123.167 us; speedup 1.0000x reference)
//
#include <hip/hip_runtime.h>

#define T_STEPS 60
#define WARMUP  29
#define HID     32
#define CT      240   // 4 * T_STEPS

__device__ __forceinline__ float fexp2(float x) { return __builtin_amdgcn_exp2f(x); }
__device__ __forceinline__ float frcp(float x)  { return __builtin_amdgcn_rcpf(x); }
__device__ __forceinline__ float sigmoid_f(float x) {
    return frcp(1.0f + fexp2(-1.4426950408889634f * x));
}
__device__ __forceinline__ float tanh_f(float x) {
    float e = fexp2(2.8853900817779268f * x);
    return 1.0f - 2.0f * frcp(e + 1.0f);
}

// Broadcast the value held by lane K of each 32-lane half to all lanes of that
// half. ds_swizzle BitMode: offset = K<<5 (and=0, or=K, xor=0). Register-only.
template<int K>
__device__ __forceinline__ float bcast(float x) {
    return __int_as_float(__builtin_amdgcn_ds_swizzle(__float_as_int(x), (K << 5)));
}

#define GATHER32(vv, xx) do { \
    vv[0]  = bcast<0>(xx);  vv[1]  = bcast<1>(xx);  vv[2]  = bcast<2>(xx);  vv[3]  = bcast<3>(xx);  \
    vv[4]  = bcast<4>(xx);  vv[5]  = bcast<5>(xx);  vv[6]  = bcast<6>(xx);  vv[7]  = bcast<7>(xx);  \
    vv[8]  = bcast<8>(xx);  vv[9]  = bcast<9>(xx);  vv[10] = bcast<10>(xx); vv[11] = bcast<11>(xx); \
    vv[12] = bcast<12>(xx); vv[13] = bcast<13>(xx); vv[14] = bcast<14>(xx); vv[15] = bcast<15>(xx); \
    vv[16] = bcast<16>(xx); vv[17] = bcast<17>(xx); vv[18] = bcast<18>(xx); vv[19] = bcast<19>(xx); \
    vv[20] = bcast<20>(xx); vv[21] = bcast<21>(xx); vv[22] = bcast<22>(xx); vv[23] = bcast<23>(xx); \
    vv[24] = bcast<24>(xx); vv[25] = bcast<25>(xx); vv[26] = bcast<26>(xx); vv[27] = bcast<27>(xx); \
    vv[28] = bcast<28>(xx); vv[29] = bcast<29>(xx); vv[30] = bcast<30>(xx); vv[31] = bcast<31>(xx); \
} while (0)

// Two batches (A,B) per lane, chains interleaved at source level. Each batch's
// accumulation order is bitwise-identical to the passing round-1 kernel:
// bias -> k=0..3 ih -> k=0..31 hh per gate, sequential fma chains;
// n = tanh(fma(r,gnh,gni)); x = fma(z, x-n, n); proj = bias + 32-fma chain.
// Weight values (AGPR-parked by the RA) are read once per step and feed BOTH
// batches' fmas — amortizing the per-use copy tax measured in rounds 1-6.
#define GRU_STEP2() do {                                                       \
    float grA = bgr, gzA = bgz, gniA = bgni, gnhA = bgnh;                      \
    float grB = bgr, gzB = bgz, gniB = bgni, gnhB = bgnh;                      \
    _Pragma("unroll")                                                          \
    for (int c = 0; c < 4; ++c) {                                              \
        grA  = __builtin_fmaf(wir[c], ua[c], grA);                             \
        grB  = __builtin_fmaf(wir[c], ub[c], grB);                             \
        gzA  = __builtin_fmaf(wiz[c], ua[c], gzA);                             \
        gzB  = __builtin_fmaf(wiz[c], ub[c], gzB);                             \
        gniA = __builtin_fmaf(win[c], ua[c], gniA);                            \
        gniB = __builtin_fmaf(win[c], ub[c], gniB);                            \
    }                                                                          \
    _Pragma("unroll")                                                          \
    for (int k = 0; k < HID; ++k) {                                            \
        grA  = __builtin_fmaf(whr[k], va[k], grA);                             \
        grB  = __builtin_fmaf(whr[k], vb[k], grB);                             \
        gzA  = __builtin_fmaf(whz[k], va[k], gzA);                             \
        gzB  = __builtin_fmaf(whz[k], vb[k], gzB);                             \
        gnhA = __builtin_fmaf(whn[k], va[k], gnhA);                            \
        gnhB = __builtin_fmaf(whn[k], vb[k], gnhB);                            \
    }                                                                          \
    float rA = sigmoid_f(grA);                                                 \
    float rB = sigmoid_f(grB);                                                 \
    float zA = sigmoid_f(gzA);                                                 \
    float zB = sigmoid_f(gzB);                                                 \
    float nA = tanh_f(__builtin_fmaf(rA, gnhA, gniA));                         \
    float nB = tanh_f(__builtin_fmaf(rB, gnhB, gniB));                         \
    xa = __builtin_fmaf(zA, xa - nA, nA);                                      \
    xb = __builtin_fmaf(zB, xb - nB, nB);                                      \
    GATHER32(va, xa);                                                          \
    GATHER32(vb, xb);                                                          \
    oa = bl; ob = bl;                                                          \
    _Pragma("unroll")                                                          \
    for (int k = 0; k < HID; ++k) {                                            \
        oa = __builtin_fmaf(wlr[k], va[k], oa);                                \
        ob = __builtin_fmaf(wlr[k], vb[k], ob);                                \
    }                                                                          \
} while (0)

// Lane j of each 32-lane half owns hidden unit j of TWO batch elements.
// No waves_per_eu attribute: let the RA pick 1 or 2 waves/SIMD freely —
// either outcome amortizes the per-step fixed cost across 4 batches/wave.
__global__ __launch_bounds__(256) void gru_fused(
    const float* __restrict__ in,
    const float* __restrict__ w_ih,  const float* __restrict__ w_hh,
    const float* __restrict__ b_ih,  const float* __restrict__ b_hh,
    const float* __restrict__ w_lin, const float* __restrict__ b_lin,
    float* __restrict__ out, float* __restrict__ h28out, int B)
{
    const int lane = threadIdx.x & 63;
    const int j    = lane & 31;                 // hidden unit owned by this lane
    const int wv   = threadIdx.x >> 6;          // wave index in block
    const int s    = lane >> 5;                 // half index within wave
    const int bA   = blockIdx.x * 16 + wv * 4 + s * 2;   // batches A and A+1
    const int bB   = bA + 1;

    // ---- one-time: load resident weights (rows of this lane's hidden unit) ----
    float whr[HID], whz[HID], whn[HID], wlr[HID];
    float wir[4], wiz[4], win[4];
    {
        const float4* pr = (const float4*)(w_hh + (size_t)j * HID);
        const float4* pz = (const float4*)(w_hh + (size_t)(HID + j) * HID);
        const float4* pn = (const float4*)(w_hh + (size_t)(2 * HID + j) * HID);
        const float4* pl = (const float4*)(w_lin + (size_t)(j & 3) * HID);
#pragma unroll
        for (int q = 0; q < 8; ++q) {
            float4 a = pr[q];
            whr[4*q] = a.x; whr[4*q+1] = a.y; whr[4*q+2] = a.z; whr[4*q+3] = a.w;
            float4 c = pz[q];
            whz[4*q] = c.x; whz[4*q+1] = c.y; whz[4*q+2] = c.z; whz[4*q+3] = c.w;
            float4 d = pn[q];
            whn[4*q] = d.x; whn[4*q+1] = d.y; whn[4*q+2] = d.z; whn[4*q+3] = d.w;
            float4 e = pl[q];
            wlr[4*q] = e.x; wlr[4*q+1] = e.y; wlr[4*q+2] = e.z; wlr[4*q+3] = e.w;
        }
        float4 a = ((const float4*)w_ih)[j];
        wir[0] = a.x; wir[1] = a.y; wir[2] = a.z; wir[3] = a.w;
        float4 c = ((const float4*)w_ih)[HID + j];
        wiz[0] = c.x; wiz[1] = c.y; wiz[2] = c.z; wiz[3] = c.w;
        float4 d = ((const float4*)w_ih)[2 * HID + j];
        win[0] = d.x; win[1] = d.y; win[2] = d.z; win[3] = d.w;
    }
    const float bgr  = b_ih[j]           + b_hh[j];
    const float bgz  = b_ih[HID + j]     + b_hh[HID + j];
    const float bgni = b_ih[2 * HID + j];
    const float bgnh = b_hh[2 * HID + j];
    const float bl   = b_lin[j & 3];

    float va[HID], vb[HID], ua[4], ub[4];
    float xa = 0.0f, xb = 0.0f, oa = 0.0f, ob = 0.0f;
#pragma unroll
    for (int k = 0; k < HID; ++k) { va[k] = 0.0f; vb[k] = 0.0f; }   // h0 = 0

    const float* pinA  = in  + (size_t)bA * CT;                     // [4][60] row
    const float* pinB  = in  + (size_t)bB * CT;
    float*       poutA = out + (size_t)bA * CT + (j & 3) * T_STEPS; // used when j<4
    float*       poutB = out + (size_t)bB * CT + (j & 3) * T_STEPS;

    // Phase 1: warmup — input from ground truth
#pragma unroll 1
    for (int t = 0; t < WARMUP; ++t) {
        ua[0] = pinA[t];       ub[0] = pinB[t];
        ua[1] = pinA[60 + t];  ub[1] = pinB[60 + t];
        ua[2] = pinA[120 + t]; ub[2] = pinB[120 + t];
        ua[3] = pinA[180 + t]; ub[3] = pinB[180 + t];
        GRU_STEP2();
        if (j < 4) { poutA[t] = oa; poutB[t] = ob; }
    }

    // h after step t == WARMUP-1
    h28out[(size_t)bA * HID + j] = xa;
    h28out[(size_t)bB * HID + j] = xb;

    // Phase 2: feedback — lanes 0..3 of each half hold o_0..o_3 per batch
#pragma unroll 1
    for (int t = WARMUP; t < T_STEPS; ++t) {
        ua[0] = bcast<0>(oa);  ub[0] = bcast<0>(ob);
        ua[1] = bcast<1>(oa);  ub[1] = bcast<1>(ob);
        ua[2] = bcast<2>(oa);  ub[2] = bcast<2>(ob);
        ua[3] = bcast<3>(oa);  ub[3] = bcast<3>(ob);
        GRU_STEP2();
        if (j < 4) { poutA[t] = oa; poutB[t] = ob; }
    }
}

extern "C" void kernel_launch(void* const* d_in, const int* in_sizes, int n_in,
                              void* d_out, int out_size, void* d_ws, size_t ws_size,
                              hipStream_t stream) {
    const float* input = (const float*)d_in[0];
    const float* w_ih  = (const float*)d_in[1];
    const float* w_hh  = (const float*)d_in[2];
    const float* b_ih  = (const float*)d_in[3];
    const float* b_hh  = (const float*)d_in[4];
    const float* w_lin = (const float*)d_in[5];
    const float* b_lin = (const float*)d_in[6];

    const int B = in_sizes[0] / CT;          // 131072
    float* out = (float*)d_out;              // [B][240]
    float* h28 = out + (size_t)B * CT;       // [B][32]
    (void)d_ws; (void)ws_size;

    hipLaunchKernelGGL(gru_fused, dim3(B / 16), dim3(256), 0, stream,
                       input, w_ih, w_hh, b_ih, b_hh, w_lin, b_lin, out, h28, B);
}